// Round 1
// baseline (1407.567 us; speedup 1.0000x reference)
//
#include <hip/hip_runtime.h>
#include <cmath>

typedef short short8 __attribute__((ext_vector_type(8)));
typedef float floatx4 __attribute__((ext_vector_type(4)));

#define T_LEN 4096
#define HC 256
#define NPOS (32 * 4096)
#define OUT_ELEMS (32 * 4 * 4096)

__device__ __forceinline__ ushort f2bf(float f) {
    uint u = __float_as_uint(f);
    u += 0x7FFFu + ((u >> 16) & 1u);
    return (ushort)(u >> 16);
}
__device__ __forceinline__ float bf2f(ushort u) {
    return __uint_as_float(((uint)u) << 16);
}
__device__ __forceinline__ float gelu_f(float x) {
    return 0.5f * x * (1.f + erff(x * 0.70710678118654752f));
}
__device__ __forceinline__ float softplus_f(float x) {
    return (x > 20.f) ? x : log1pf(expf(x));
}

// ---------------------------------------------------------------- prep ----
// conv1_w (4*256*256 f32) -> bf16 same layout; proj_w (58x256) -> bf16 padded to 64 rows
__global__ __launch_bounds__(256) void prep_kernel(
    const float* __restrict__ cw, const float* __restrict__ pw,
    ushort* __restrict__ wbf, ushort* __restrict__ pwbf)
{
    int idx = blockIdx.x * 256 + threadIdx.x;
    if (idx < 4 * 256 * 256) {
        wbf[idx] = f2bf(cw[idx]);
    } else if (idx < 4 * 256 * 256 + 64 * 256) {
        int j = idx - 4 * 256 * 256;
        int row = j >> 8, c = j & 255;
        pwbf[j] = (row < 58) ? f2bf(pw[row * 256 + c]) : (ushort)0;
    }
}

// ----------------------------------------------------------------- pre ----
// h[p][o] = pre_w[o][0]*x0a + pre_w[o][1]*x0b + pre_b[o]; also copy x0->out, zero logdet
__global__ __launch_bounds__(256) void pre_kernel(
    const float* __restrict__ x, const float* __restrict__ mask,
    const float* __restrict__ pre_w, const float* __restrict__ pre_b,
    ushort* __restrict__ h, float* __restrict__ out)
{
    const int t = threadIdx.x;
    const int p0 = blockIdx.x * 2;
    const int p = p0 + (t >> 7);
    const int o = (t & 127) * 2;
    const int b = p >> 12;
    const int tt = p & 4095;
    const float xa = x[b * 16384 + tt];
    const float xb = x[b * 16384 + 4096 + tt];
    const float4 w = *(const float4*)(pre_w + 2 * o);
    const float v0 = w.x * xa + w.y * xb + pre_b[o];
    const float v1 = w.z * xa + w.w * xb + pre_b[o + 1];
    const uint pk = (uint)f2bf(v0) | ((uint)f2bf(v1) << 16);
    *(uint*)(h + (size_t)p * HC + o) = pk;
    if (t < 4) {
        const int pp = p0 + (t >> 1);
        const int bb = pp >> 12, t2 = pp & 4095;
        const int ch = t & 1;
        out[bb * 16384 + ch * 4096 + t2] = x[bb * 16384 + ch * 4096 + t2] * mask[bb * 4096 + t2];
    }
    if (blockIdx.x == 0 && t >= 64 && t < 96) out[OUT_ELEMS + (t - 64)] = 0.f;
}

// --------------------------------------------------------------- layer ----
// fused: dwconv(dil)+LN+gelu -> LDS(bf16) ; MFMA 256x256 ; bias+LN+gelu+residual -> hout
__global__ __launch_bounds__(256) void layer_kernel(
    const ushort* __restrict__ hin, ushort* __restrict__ hout,
    const ushort* __restrict__ wbf,
    const float* __restrict__ sep_w, const float* __restrict__ sep_b,
    const float* __restrict__ conv1_b,
    const float* __restrict__ n1g, const float* __restrict__ n1b,
    const float* __restrict__ n2g, const float* __restrict__ n2b,
    const float* __restrict__ mask, int dil)
{
    __shared__ __align__(16) ushort ylds[64 * 264];   // 64 pos x 256ch, stride 264 (pad)
    __shared__ __align__(16) ushort wlds[256 * 40];   // 256 out x 32ch k-slice, stride 40 (pad)

    const int tid = threadIdx.x;
    const int lane = tid & 63;
    const int wv = tid >> 6;
    const int blk = blockIdx.x;
    const int b = blk >> 6;
    const int t0 = (blk & 63) << 6;
    const float* maskb = mask + b * T_LEN;
    const size_t hbase = (size_t)b * T_LEN * HC;

    // ---- phase 1: depthwise conv + LN(n1) + gelu -> ylds bf16 ----
    {
        const int c0 = lane * 4;   // channels c0..c0+3
        float sw[12];
        *(float4*)(sw + 0) = *(const float4*)(sep_w + c0 * 3 + 0);
        *(float4*)(sw + 4) = *(const float4*)(sep_w + c0 * 3 + 4);
        *(float4*)(sw + 8) = *(const float4*)(sep_w + c0 * 3 + 8);
        float sbv[4], g1v[4], b1v[4];
        *(float4*)sbv = *(const float4*)(sep_b + c0);
        *(float4*)g1v = *(const float4*)(n1g + c0);
        *(float4*)b1v = *(const float4*)(n1b + c0);

        for (int m = 0; m < 16; ++m) {
            const int t = t0 + wv * 16 + m;   // wave-uniform
            float hm[4] = {0.f, 0.f, 0.f, 0.f};
            float hp[4] = {0.f, 0.f, 0.f, 0.f};
            float hcv[4];
            {
                const float mc = maskb[t];
                uint2 r = *(const uint2*)(hin + hbase + (size_t)t * HC + c0);
                hcv[0] = bf2f((ushort)(r.x & 0xffffu)) * mc;
                hcv[1] = bf2f((ushort)(r.x >> 16)) * mc;
                hcv[2] = bf2f((ushort)(r.y & 0xffffu)) * mc;
                hcv[3] = bf2f((ushort)(r.y >> 16)) * mc;
            }
            if (t - dil >= 0) {
                const float mm = maskb[t - dil];
                uint2 r = *(const uint2*)(hin + hbase + (size_t)(t - dil) * HC + c0);
                hm[0] = bf2f((ushort)(r.x & 0xffffu)) * mm;
                hm[1] = bf2f((ushort)(r.x >> 16)) * mm;
                hm[2] = bf2f((ushort)(r.y & 0xffffu)) * mm;
                hm[3] = bf2f((ushort)(r.y >> 16)) * mm;
            }
            if (t + dil < T_LEN) {
                const float mp = maskb[t + dil];
                uint2 r = *(const uint2*)(hin + hbase + (size_t)(t + dil) * HC + c0);
                hp[0] = bf2f((ushort)(r.x & 0xffffu)) * mp;
                hp[1] = bf2f((ushort)(r.x >> 16)) * mp;
                hp[2] = bf2f((ushort)(r.y & 0xffffu)) * mp;
                hp[3] = bf2f((ushort)(r.y >> 16)) * mp;
            }
            float v[4];
            #pragma unroll
            for (int j = 0; j < 4; ++j)
                v[j] = sw[3 * j] * hm[j] + sw[3 * j + 1] * hcv[j] + sw[3 * j + 2] * hp[j] + sbv[j];
            float s = v[0] + v[1] + v[2] + v[3];
            float q = v[0] * v[0] + v[1] * v[1] + v[2] * v[2] + v[3] * v[3];
            #pragma unroll
            for (int d = 32; d > 0; d >>= 1) {
                s += __shfl_xor(s, d, 64);
                q += __shfl_xor(q, d, 64);
            }
            const float mean = s * (1.f / 256.f);
            const float var = q * (1.f / 256.f) - mean * mean;
            const float rs = rsqrtf(var + 1e-5f);
            const float y0 = gelu_f((v[0] - mean) * rs * g1v[0] + b1v[0]);
            const float y1 = gelu_f((v[1] - mean) * rs * g1v[1] + b1v[1]);
            const float y2 = gelu_f((v[2] - mean) * rs * g1v[2] + b1v[2]);
            const float y3 = gelu_f((v[3] - mean) * rs * g1v[3] + b1v[3]);
            const uint pk0 = (uint)f2bf(y0) | ((uint)f2bf(y1) << 16);
            const uint pk1 = (uint)f2bf(y2) | ((uint)f2bf(y3) << 16);
            *(uint2*)(&ylds[(wv * 16 + m) * 264 + c0]) = make_uint2(pk0, pk1);
        }
    }

    // ---- phase 2: MFMA — wave handles 16 positions x 256 outputs ----
    const int lw = lane & 15;
    const int quad = lane >> 4;
    floatx4 acc[16];
    #pragma unroll
    for (int n = 0; n < 16; ++n) acc[n] = (floatx4){0.f, 0.f, 0.f, 0.f};

    for (int kt = 0; kt < 8; ++kt) {
        __syncthreads();   // kt=0: ylds ready; kt>0: prev wlds reads done
        #pragma unroll
        for (int jj = 0; jj < 4; ++jj) {
            const int idx = jj * 256 + tid;       // 1024 chunks of 16B
            const int row = idx >> 2, seg = idx & 3;
            short8 vv = *(const short8*)(wbf + row * 256 + kt * 32 + seg * 8);
            *(short8*)(&wlds[row * 40 + seg * 8]) = vv;
        }
        __syncthreads();
        short8 a = *(short8*)(&ylds[(wv * 16 + lw) * 264 + kt * 32 + quad * 8]);
        #pragma unroll
        for (int n = 0; n < 16; ++n) {
            short8 bb = *(short8*)(&wlds[(n * 16 + lw) * 40 + quad * 8]);
            acc[n] = __builtin_amdgcn_mfma_f32_16x16x32_bf16(a, bb, acc[n], 0, 0, 0);
        }
    }

    // ---- epilogue: bias + LN(n2) + gelu + residual ----
    float sum[4] = {0, 0, 0, 0}, sq[4] = {0, 0, 0, 0};
    #pragma unroll
    for (int n = 0; n < 16; ++n) {
        const float cb = conv1_b[n * 16 + lw];
        #pragma unroll
        for (int r = 0; r < 4; ++r) {
            const float val = acc[n][r] + cb;
            acc[n][r] = val;
            sum[r] += val;
            sq[r] += val * val;
        }
    }
    #pragma unroll
    for (int d = 1; d < 16; d <<= 1) {
        #pragma unroll
        for (int r = 0; r < 4; ++r) {
            sum[r] += __shfl_xor(sum[r], d, 64);
            sq[r] += __shfl_xor(sq[r], d, 64);
        }
    }
    float mean[4], rsv[4];
    #pragma unroll
    for (int r = 0; r < 4; ++r) {
        mean[r] = sum[r] * (1.f / 256.f);
        const float var = sq[r] * (1.f / 256.f) - mean[r] * mean[r];
        rsv[r] = rsqrtf(var + 1e-5f);
    }
    #pragma unroll
    for (int n = 0; n < 16; ++n) {
        const int o = n * 16 + lw;
        const float g2 = n2g[o], b2 = n2b[o];
        #pragma unroll
        for (int r = 0; r < 4; ++r) {
            const int t = t0 + wv * 16 + quad * 4 + r;
            const size_t addr = hbase + (size_t)t * HC + o;
            const float y = gelu_f((acc[n][r] - mean[r]) * rsv[r] * g2 + b2);
            hout[addr] = f2bf(bf2f(hin[addr]) + y);
        }
    }
}

// ---------------------------------------------------------- proj+spline ----
__global__ __launch_bounds__(256) void proj_kernel(
    const ushort* __restrict__ hin, const ushort* __restrict__ pwbf,
    const float* __restrict__ projb, const float* __restrict__ x,
    const float* __restrict__ mask, float* __restrict__ out)
{
    __shared__ __align__(16) ushort alds[64 * 264];
    __shared__ float slds[64 * 65];
    __shared__ float red[4];

    const int tid = threadIdx.x;
    const int lane = tid & 63;
    const int wv = tid >> 6;
    const int blk = blockIdx.x;
    const int b = blk >> 6;
    const int t0 = (blk & 63) << 6;
    const size_t hbase = (size_t)b * T_LEN * HC;

    #pragma unroll
    for (int jj = 0; jj < 8; ++jj) {
        const int idx = jj * 256 + tid;           // 2048 chunks of 16B
        const int row = idx >> 5, seg = idx & 31;
        short8 v = *(const short8*)(hin + hbase + (size_t)(t0 + row) * HC + seg * 8);
        *(short8*)(&alds[row * 264 + seg * 8]) = v;
    }
    __syncthreads();

    const int lw = lane & 15;
    const int quad = lane >> 4;
    floatx4 acc[4];
    #pragma unroll
    for (int n = 0; n < 4; ++n) acc[n] = (floatx4){0.f, 0.f, 0.f, 0.f};
    #pragma unroll
    for (int kt = 0; kt < 8; ++kt) {
        short8 a = *(short8*)(&alds[(wv * 16 + lw) * 264 + kt * 32 + quad * 8]);
        #pragma unroll
        for (int n = 0; n < 4; ++n) {
            short8 bb = *(const short8*)(pwbf + (n * 16 + lw) * 256 + kt * 32 + quad * 8);
            acc[n] = __builtin_amdgcn_mfma_f32_16x16x32_bf16(a, bb, acc[n], 0, 0, 0);
        }
    }
    #pragma unroll
    for (int n = 0; n < 4; ++n) {
        const int o = n * 16 + lw;
        const float pb = (o < 58) ? projb[o] : 0.f;
        #pragma unroll
        for (int r = 0; r < 4; ++r) {
            const int row = wv * 16 + quad * 4 + r;
            const float mv = mask[b * T_LEN + t0 + row];
            slds[row * 65 + o] = acc[n][r] * mv + pb;   // mask folded: mask*(W.h) + b
        }
    }
    __syncthreads();

    float contrib = 0.f;
    if (tid < 128) {
        const int pos = tid >> 1;
        const int ch = tid & 1;
        const int t = t0 + pos;
        float sv[29];
        #pragma unroll
        for (int j = 0; j < 29; ++j) sv[j] = slds[pos * 65 + ch * 29 + j];
        const float x1 = x[b * 16384 + (2 + ch) * 4096 + t];

        const float SC = 0.0625f;  // 1/sqrt(256)
        float cwv[11], wdv[10], chv[11], htv[10], dvv[11];
        {   // widths
            float u[10];
            float mx = -1e30f;
            #pragma unroll
            for (int j = 0; j < 10; ++j) { u[j] = sv[j] * SC; mx = fmaxf(mx, u[j]); }
            float ssum = 0.f;
            #pragma unroll
            for (int j = 0; j < 10; ++j) { u[j] = expf(u[j] - mx); ssum += u[j]; }
            const float inv = 1.f / ssum;
            float cum = 0.f;
            cwv[0] = -5.f;
            #pragma unroll
            for (int j = 0; j < 10; ++j) {
                cum += 0.001f + 0.99f * u[j] * inv;
                cwv[j + 1] = 10.f * cum - 5.f;
            }
            cwv[10] = 5.f;
            #pragma unroll
            for (int j = 0; j < 10; ++j) wdv[j] = cwv[j + 1] - cwv[j];
        }
        {   // heights
            float u[10];
            float mx = -1e30f;
            #pragma unroll
            for (int j = 0; j < 10; ++j) { u[j] = sv[10 + j] * SC; mx = fmaxf(mx, u[j]); }
            float ssum = 0.f;
            #pragma unroll
            for (int j = 0; j < 10; ++j) { u[j] = expf(u[j] - mx); ssum += u[j]; }
            const float inv = 1.f / ssum;
            float cum = 0.f;
            chv[0] = -5.f;
            #pragma unroll
            for (int j = 0; j < 10; ++j) {
                cum += 0.001f + 0.99f * u[j] * inv;
                chv[j + 1] = 10.f * cum - 5.f;
            }
            chv[10] = 5.f;
            #pragma unroll
            for (int j = 0; j < 10; ++j) htv[j] = chv[j + 1] - chv[j];
        }
        dvv[0] = 1.f;
        dvv[10] = 1.f;
        #pragma unroll
        for (int j = 1; j <= 9; ++j) dvv[j] = 0.001f + softplus_f(sv[19 + j]);

        const bool inside = (x1 >= -5.f) && (x1 <= 5.f);
        const float xc = fminf(fmaxf(x1, -5.f), 5.f);
        float in_cw = cwv[0], in_w = wdv[0], in_ch = chv[0], in_h = htv[0];
        float dk = dvv[0], dk1 = dvv[1];
        #pragma unroll
        for (int j = 1; j < 10; ++j) {
            const bool ge = (xc >= cwv[j]);
            in_cw = ge ? cwv[j] : in_cw;
            in_w  = ge ? wdv[j] : in_w;
            in_ch = ge ? chv[j] : in_ch;
            in_h  = ge ? htv[j] : in_h;
            dk    = ge ? dvv[j] : dk;
            dk1   = ge ? dvv[j + 1] : dk1;
        }
        const float th = (xc - in_cw) / in_w;
        const float t1m = th * (1.f - th);
        const float dl = in_h / in_w;
        const float num = in_h * (dl * th * th + dk * t1m);
        const float den = dl + (dk + dk1 - 2.f * dl) * t1m;
        float yv = in_ch + num / den;
        const float omt = 1.f - th;
        const float dnum = dl * dl * (dk1 * th * th + 2.f * dl * t1m + dk * omt * omt);
        float lad = logf(dnum) - 2.f * logf(den);
        if (!inside) { yv = x1; lad = 0.f; }
        const float mv = mask[b * T_LEN + t];
        out[b * 16384 + (2 + ch) * 4096 + t] = yv * mv;
        contrib = lad * mv;
    }
    #pragma unroll
    for (int d = 32; d > 0; d >>= 1) contrib += __shfl_xor(contrib, d, 64);
    if (lane == 0) red[wv] = contrib;
    __syncthreads();
    if (tid == 0) atomicAdd(out + OUT_ELEMS + b, red[0] + red[1] + red[2] + red[3]);
}

// -------------------------------------------------------------- launch ----
extern "C" void kernel_launch(void* const* d_in, const int* in_sizes, int n_in,
                              void* d_out, int out_size, void* d_ws, size_t ws_size,
                              hipStream_t stream) {
    const float* x      = (const float*)d_in[0];
    const float* mask   = (const float*)d_in[1];
    const float* pre_w  = (const float*)d_in[2];
    const float* pre_b  = (const float*)d_in[3];
    const float* sep_w  = (const float*)d_in[4];
    const float* sep_b  = (const float*)d_in[5];
    const float* conv1w = (const float*)d_in[6];
    const float* conv1b = (const float*)d_in[7];
    const float* n1g    = (const float*)d_in[8];
    const float* n1b    = (const float*)d_in[9];
    const float* n2g    = (const float*)d_in[10];
    const float* n2b    = (const float*)d_in[11];
    const float* projw  = (const float*)d_in[12];
    const float* projb  = (const float*)d_in[13];
    float* out = (float*)d_out;

    ushort* h0   = (ushort*)d_ws;
    ushort* h1   = h0 + (size_t)NPOS * HC;
    ushort* wbf  = h1 + (size_t)NPOS * HC;
    ushort* pwbf = wbf + 4 * 256 * 256;

    prep_kernel<<<1088, 256, 0, stream>>>(conv1w, projw, wbf, pwbf);
    pre_kernel<<<NPOS / 2, 256, 0, stream>>>(x, mask, pre_w, pre_b, h0, out);

    int dil = 1;
    ushort* src = h0;
    ushort* dst = h1;
    for (int i = 0; i < 4; ++i) {
        layer_kernel<<<2048, 256, 0, stream>>>(src, dst, wbf + i * 65536,
            sep_w + i * 768, sep_b + i * 256, conv1b + i * 256,
            n1g + i * 256, n1b + i * 256, n2g + i * 256, n2b + i * 256, mask, dil);
        dil *= 3;
        ushort* tmp = src; src = dst; dst = tmp;
    }
    proj_kernel<<<2048, 256, 0, stream>>>(src, pwbf, projb, x, mask, out);
}